// Round 7
// baseline (610.043 us; speedup 1.0000x reference)
//
#include <hip/hip_runtime.h>
#include <cstdint>

// ---------------------------------------------------------------------------
// SnLocalDecoder: B=4, n=48, C=32. Round-7 = R6 composite with ONE surgical
// change: k_vw / k_final sweep LDS layout transposed to [c][pos] (stride 132)
// so each sweep step is one aligned conflict-free ds_read_b128 (4 positions x
// 1 channel) instead of 4 scalar b32 reads. 4x fewer sweep LDS insts; s
// buffer reuses sA (LDS 52.2 -> 33.8 KB, 4 blocks/CU). Thread->output map,
// wc-in-registers, finish code, global patterns unchanged (R4/R5 lesson:
// big k_vw rewrites trigger codegen pathologies; keep deltas minimal).
// ---------------------------------------------------------------------------

namespace {

constexpr int nB = 4, nN = 48, nC = 32;
constexpr int SJ_ = nN * nC;            // 1536
constexpr int SI_ = nN * SJ_;           // 73728
constexpr long SB_ = (long)nN * SI_;    // 3538944
constexpr int CP_ = 294912;             // cols-partial stride
constexpr int TP_ = 6144;               // tot-partial stride
constexpr int CS_ = 132;                // [c][pos] LDS row stride (4-aligned, 33-quad)

__device__ __forceinline__ void decodePos(int p, int& b, int& i, int& j, int& m) {
    m = p % nN; int r = p / nN;
    j = r % nN; r /= nN;
    i = r % nN; b = r / nN;
}

// ---------------------------------------------------------------------------
__global__ __launch_bounds__(256) void k_prep(const float* __restrict__ x,
                                              const void* __restrict__ maskp,
                                              float* __restrict__ vm,
                                              float* __restrict__ S)
{
    __shared__ float vmL[nB * nN];
    const int tid = threadIdx.x;
    const unsigned int w0 = *(const unsigned int*)maskp;
    const bool is_byte = (w0 == 0x01010101u);   // bool-byte layout
    if (tid < nB * nN) {
        int b = tid / nN, i = tid % nN;
        long idx = ((long)(b * nN + i) * nN + i) * nN + i;   // mask[b,i,i,i]
        int bit;
        if (is_byte) bit = (((const unsigned char*)maskp)[idx] != 0);
        else         bit = (((const int*)maskp)[idx] != 0);
        float f = bit ? 1.f : 0.f;
        vm[tid] = f; vmL[tid] = f;
    }
    __syncthreads();
    if (tid < nB * nC) {
        int b = tid >> 5, c = tid & 31;
        float s = 0.f;
        for (int j = 0; j < nN; ++j) s += x[(b * nN + j) * nC + c] * vmL[b * nN + j];
        S[tid] = s;
    }
}

// ---------------------------------------------------------------------------
// Layer-0 small snconv2 terms, closed form from x and S.
__global__ __launch_bounds__(256) void k_mix0(
    const float* __restrict__ x, const float* __restrict__ S,
    const float* __restrict__ Wb, const float* __restrict__ bias,
    float* __restrict__ drp, float* __restrict__ ccp, float* __restrict__ tbp)
{
    __shared__ float W2s[1024], W3s[1024], W4s[1024], W5s[1024], bs[32];
    const int tid = threadIdx.x;
    for (int q = tid; q < 1024; q += 256) {
        W2s[q] = Wb[2048 + q]; W3s[q] = Wb[3072 + q];
        W4s[q] = Wb[4096 + q]; W5s[q] = Wb[5120 + q];
    }
    if (tid < 32) bs[tid] = bias[tid];
    __syncthreads();
    const int id = blockIdx.x * 256 + tid;        // (b*48+i)*48+m
    const int m = id % nN; int r = id / nN; const int i = r % nN; const int b = r / nN;
    float odr[32], occ[32];
    #pragma unroll
    for (int d = 0; d < 32; ++d) { odr[d] = 0.f; occ[d] = 0.f; }
    for (int c2 = 0; c2 < 32; ++c2) {
        float xi = x[(b * nN + i) * nC + c2];
        float xm = x[(b * nN + m) * nC + c2];
        float sc = S[b * nC + c2];
        float A = xi * xi * xm;
        float R = xi * xm * sc * (1.f / nN);
        #pragma unroll
        for (int d = 0; d < 32; ++d) {
            odr[d] = fmaf(A, W2s[c2 * 32 + d], fmaf(R, W3s[c2 * 32 + d], odr[d]));
            occ[d] = fmaf(R, W4s[c2 * 32 + d], occ[d]);
        }
    }
    #pragma unroll
    for (int d = 0; d < 32; d += 4) {
        *(float4*)(drp + (size_t)id * 32 + d) = make_float4(odr[d], odr[d+1], odr[d+2], odr[d+3]);
        *(float4*)(ccp + (size_t)id * 32 + d) = make_float4(occ[d], occ[d+1], occ[d+2], occ[d+3]);
    }
    if (i == 0) {
        float ot[32];
        #pragma unroll
        for (int d = 0; d < 32; ++d) ot[d] = bs[d];
        for (int c2 = 0; c2 < 32; ++c2) {
            float xm = x[(b * nN + m) * nC + c2];
            float sc = S[b * nC + c2];
            float Tc = xm * sc * sc * (1.f / (nN * nN));
            #pragma unroll
            for (int d = 0; d < 32; ++d) ot[d] = fmaf(Tc, W5s[c2 * 32 + d], ot[d]);
        }
        for (int d = 0; d < 32; d += 4)
            *(float4*)(tbp + (size_t)(b * nN + m) * 32 + d) = make_float4(ot[d], ot[d+1], ot[d+2], ot[d+3]);
    }
}

// ---------------------------------------------------------------------------
// Generic small snconv2 terms; cols/tot arrive as 4 i-quarter partials.
template <int DOUT>
__global__ __launch_bounds__(256) void k_mix(
    const float* __restrict__ dgp, const float* __restrict__ rwp,
    const float* __restrict__ clp4, const float* __restrict__ ttp4,
    const float* __restrict__ Wb, const float* __restrict__ bias,
    float* __restrict__ drp, float* __restrict__ ccp, float* __restrict__ tbp)
{
    __shared__ float W2s[32 * DOUT], W3s[32 * DOUT], W4s[32 * DOUT], W5s[32 * DOUT], bs[DOUT];
    const int tid = threadIdx.x;
    for (int q = tid; q < 32 * DOUT; q += 256) {
        W2s[q] = Wb[2 * 32 * DOUT + q]; W3s[q] = Wb[3 * 32 * DOUT + q];
        W4s[q] = Wb[4 * 32 * DOUT + q]; W5s[q] = Wb[5 * 32 * DOUT + q];
    }
    if (tid < DOUT) bs[tid] = bias[tid];
    __syncthreads();
    const int id = blockIdx.x * 256 + tid;
    const int m = id % nN; int r = id / nN; const int i = r % nN; const int b = r / nN;
    float odr[DOUT], occ[DOUT];
    #pragma unroll
    for (int d = 0; d < DOUT; ++d) { odr[d] = 0.f; occ[d] = 0.f; }
    for (int c2 = 0; c2 < 32; ++c2) {
        size_t q = (size_t)id * 32 + c2;
        float dg = dgp[q];
        float rw = rwp[q];
        float cl = clp4[q] + clp4[q + CP_] + clp4[q + 2 * CP_] + clp4[q + 3 * CP_];
        #pragma unroll
        for (int d = 0; d < DOUT; ++d) {
            odr[d] = fmaf(dg, W2s[c2 * DOUT + d], fmaf(rw, W3s[c2 * DOUT + d], odr[d]));
            occ[d] = fmaf(cl, W4s[c2 * DOUT + d], occ[d]);
        }
    }
    #pragma unroll
    for (int d = 0; d < DOUT; d += 4) {
        *(float4*)(drp + (size_t)id * DOUT + d) = make_float4(odr[d], odr[d+1], odr[d+2], odr[d+3]);
        *(float4*)(ccp + (size_t)id * DOUT + d) = make_float4(occ[d], occ[d+1], occ[d+2], occ[d+3]);
    }
    if (i == 0) {
        float ot[DOUT];
        #pragma unroll
        for (int d = 0; d < DOUT; ++d) ot[d] = bs[d];
        for (int c2 = 0; c2 < 32; ++c2) {
            size_t q = (size_t)(b * nN + m) * 32 + c2;
            float tv = ttp4[q] + ttp4[q + TP_] + ttp4[q + 2 * TP_] + ttp4[q + 3 * TP_];
            #pragma unroll
            for (int d = 0; d < DOUT; ++d) ot[d] = fmaf(tv, W5s[c2 * DOUT + d], ot[d]);
        }
        for (int d = 0; d < DOUT; d += 4)
            *(float4*)(tbp + (size_t)(b * nN + m) * DOUT + d) = make_float4(ot[d], ot[d+1], ot[d+2], ot[d+3]);
    }
}

// ---------------------------------------------------------------------------
// Reductions of t, NO atomics: rows/diag direct; cols/tot as per-iq partials.
__global__ __launch_bounds__(256) void k_red4(
    const float* __restrict__ t,
    float* __restrict__ rows_, float* __restrict__ cols4,
    float* __restrict__ diag_, float* __restrict__ tot4)
{
    const int blk = blockIdx.x;
    const int iq = blk & 3; const int bm = blk >> 2;
    const int b = bm / nN, m = bm % nN;
    const int jg = threadIdx.x >> 5;
    const int c = threadIdx.x & 31;
    __shared__ float part[8][32];
    const size_t base = (size_t)b * SB_ + (size_t)m * nC;
    float colacc[6] = {0, 0, 0, 0, 0, 0};
    float totacc = 0.f;
    for (int ii = 0; ii < 12; ++ii) {
        const int i = iq * 12 + ii;
        float vals[6];
        #pragma unroll
        for (int jl = 0; jl < 6; ++jl) {
            int j = jg * 6 + jl;
            vals[jl] = t[base + (size_t)i * SI_ + (size_t)j * SJ_ + c];
        }
        float rp = 0.f;
        #pragma unroll
        for (int jl = 0; jl < 6; ++jl) { colacc[jl] += vals[jl]; rp += vals[jl]; }
        {
            int jd = i - jg * 6;
            if (jd >= 0 && jd < 6) diag_[((size_t)(b * nN + i) * nN + m) * nC + c] = vals[jd];
        }
        part[jg][c] = rp;
        __syncthreads();
        if (jg == 0) {
            float rv = 0.f;
            #pragma unroll
            for (int g = 0; g < 8; ++g) rv += part[g][c];
            rows_[((size_t)(b * nN + i) * nN + m) * nC + c] = rv * (1.f / nN);
            totacc += rv;
        }
        __syncthreads();
    }
    #pragma unroll
    for (int jl = 0; jl < 6; ++jl) {
        int j = jg * 6 + jl;
        cols4[(size_t)iq * CP_ + ((size_t)(b * nN + j) * nN + m) * nC + c] = colacc[jl] * (1.f / nN);
    }
    if (jg == 0)
        tot4[(size_t)iq * TP_ + (size_t)(b * nN + m) * nC + c] = totacc * (1.f / (nN * nN));
}

// ---------------------------------------------------------------------------
// s = masked(snconv2(t)); v = s@Wv+bv; w = s@Ww+bw.
// [c][pos] LDS (stride 132): sweep = 32 conflict-free ds_read_b128 / phase.
// s reuses sA after the t/tT sweeps (extra barrier). wc stays in registers.
template <int MODE>
__global__ __launch_bounds__(256) void k_vw(
    const float* __restrict__ src, const float* __restrict__ vm,
    const float* __restrict__ drp, const float* __restrict__ ccp, const float* __restrict__ tbp,
    const float* __restrict__ W0, const float* __restrict__ W1,
    const float* __restrict__ Wv, const float* __restrict__ bv,
    const float* __restrict__ Ww, const float* __restrict__ bw,
    float* __restrict__ vout, float* __restrict__ wout)
{
    __shared__ float sA[32 * CS_];
    __shared__ float sB[(MODE == 0) ? 4 : 32 * CS_];
    const int tid = threadIdx.x;
    const long base = (long)blockIdx.x * 128;

    if (MODE == 0) {
        for (int rep = 0; rep < 4; ++rep) {
            int q = rep * 256 + tid; int pl = q >> 3, cq = q & 7;
            int p = (int)base + pl;
            int b, i, j, m; decodePos(p, b, i, j, m);
            float4 xi = *(const float4*)(src + (size_t)(b * nN + i) * nC + cq * 4);
            float4 xj = *(const float4*)(src + (size_t)(b * nN + j) * nC + cq * 4);
            float4 xm = *(const float4*)(src + (size_t)(b * nN + m) * nC + cq * 4);
            sA[(cq * 4 + 0) * CS_ + pl] = xi.x * xj.x * xm.x;
            sA[(cq * 4 + 1) * CS_ + pl] = xi.y * xj.y * xm.y;
            sA[(cq * 4 + 2) * CS_ + pl] = xi.z * xj.z * xm.z;
            sA[(cq * 4 + 3) * CS_ + pl] = xi.w * xj.w * xm.w;
        }
    } else {
        for (int rep = 0; rep < 4; ++rep) {
            int q = rep * 256 + tid; int pl = q >> 3, cq = q & 7;
            long p = base + pl;
            float4 a = *(const float4*)(src + p * nC + cq * 4);
            sA[(cq * 4 + 0) * CS_ + pl] = a.x;
            sA[(cq * 4 + 1) * CS_ + pl] = a.y;
            sA[(cq * 4 + 2) * CS_ + pl] = a.z;
            sA[(cq * 4 + 3) * CS_ + pl] = a.w;
            int b, i, j, m; decodePos((int)p, b, i, j, m);
            long pT = ((long)(b * nN + j) * nN + i) * nN + m;
            float4 t4 = *(const float4*)(src + pT * nC + cq * 4);
            sB[(cq * 4 + 0) * CS_ + pl] = t4.x;
            sB[(cq * 4 + 1) * CS_ + pl] = t4.y;
            sB[(cq * 4 + 2) * CS_ + pl] = t4.z;
            sB[(cq * 4 + 3) * CS_ + pl] = t4.w;
        }
    }
    __syncthreads();

    const int pt = tid >> 3, dq = tid & 7;
    const int p0 = pt * 4, d0 = dq * 4;
    float wc[32][4];
    float acc[4][4];

    auto zeroAcc = [&]() {
        #pragma unroll
        for (int a2 = 0; a2 < 4; ++a2)
            #pragma unroll
            for (int l = 0; l < 4; ++l) acc[a2][l] = 0.f;
    };
    auto loadW = [&](const float* Wp) {
        #pragma unroll
        for (int c2 = 0; c2 < 32; ++c2) {
            float4 q4 = *(const float4*)(Wp + c2 * nC + d0);
            wc[c2][0] = q4.x; wc[c2][1] = q4.y; wc[c2][2] = q4.z; wc[c2][3] = q4.w;
        }
    };
    auto addW = [&](const float* Wp) {
        #pragma unroll
        for (int c2 = 0; c2 < 32; ++c2) {
            float4 q4 = *(const float4*)(Wp + c2 * nC + d0);
            wc[c2][0] += q4.x; wc[c2][1] += q4.y; wc[c2][2] += q4.z; wc[c2][3] += q4.w;
        }
    };
    auto sweep = [&](const float* sp) {
        #pragma unroll
        for (int c2 = 0; c2 < 32; ++c2) {
            float4 tv = *(const float4*)(sp + c2 * CS_ + p0);   // 4 positions, 1 channel
            #pragma unroll
            for (int d = 0; d < 4; ++d) {
                acc[0][d] = fmaf(tv.x, wc[c2][d], acc[0][d]);
                acc[1][d] = fmaf(tv.y, wc[c2][d], acc[1][d]);
                acc[2][d] = fmaf(tv.z, wc[c2][d], acc[2][d]);
                acc[3][d] = fmaf(tv.w, wc[c2][d], acc[3][d]);
            }
        }
    };

    zeroAcc();
    if (MODE == 0) { loadW(W0); addW(W1); sweep(sA); }
    else           { loadW(W0); sweep(sA); loadW(W1); sweep(sB); }

    // masked s -> registers, then (after barrier) into sA in [c][pos] layout
    float sv[4][4];
    #pragma unroll
    for (int l = 0; l < 4; ++l) {
        int p = (int)base + p0 + l;
        int b, i, j, m; decodePos(p, b, i, j, m);
        float4 d4 = *(const float4*)(drp + (size_t)((b * nN + i) * nN + m) * nC + d0);
        float4 c4 = *(const float4*)(ccp + (size_t)((b * nN + j) * nN + m) * nC + d0);
        float4 t4 = *(const float4*)(tbp + (size_t)(b * nN + m) * nC + d0);
        float mk = vm[b * nN + i] * vm[b * nN + j] * vm[b * nN + m];
        sv[l][0] = (acc[l][0] + d4.x + c4.x + t4.x) * mk;
        sv[l][1] = (acc[l][1] + d4.y + c4.y + t4.y) * mk;
        sv[l][2] = (acc[l][2] + d4.z + c4.z + t4.z) * mk;
        sv[l][3] = (acc[l][3] + d4.w + c4.w + t4.w) * mk;
    }
    __syncthreads();                   // all sweeps of sA/sB done
    #pragma unroll
    for (int e = 0; e < 4; ++e)
        *(float4*)(sA + (d0 + e) * CS_ + p0) =
            make_float4(sv[0][e], sv[1][e], sv[2][e], sv[3][e]);
    __syncthreads();

    // stage B: v then w
    zeroAcc(); loadW(Wv); sweep(sA);
    {
        float4 b4 = *(const float4*)(bv + d0);
        #pragma unroll
        for (int l = 0; l < 4; ++l) {
            float4 o4 = make_float4(acc[l][0] + b4.x, acc[l][1] + b4.y,
                                    acc[l][2] + b4.z, acc[l][3] + b4.w);
            *(float4*)(vout + (size_t)(base + p0 + l) * nC + d0) = o4;
        }
    }
    zeroAcc(); loadW(Ww); sweep(sA);
    {
        float4 b4 = *(const float4*)(bw + d0);
        #pragma unroll
        for (int l = 0; l < 4; ++l) {
            float4 o4 = make_float4(acc[l][0] + b4.x, acc[l][1] + b4.y,
                                    acc[l][2] + b4.z, acc[l][3] + b4.w);
            *(float4*)(wout + (size_t)(base + p0 + l) * nC + d0) = o4;
        }
    }
}

// ---------------------------------------------------------------------------
// z = V*W/n per (b,m); o-mix + relu + mask -> t.  (R3/R6 verbatim.)
__global__ __launch_bounds__(256, 3) void k_z(
    const float* __restrict__ v, const float* __restrict__ w,
    const float* __restrict__ Wo, const float* __restrict__ bo,
    const float* __restrict__ vm, float* __restrict__ tout)
{
    __shared__ float lds[12912];           // 51648 B -> 3 blocks/CU
    float* Vt = lds;                       // [kk][c][i]: kk*807 + c*25 + i
    float* Wt = lds + 6456;
    const int tid = threadIdx.x;
    const int blk = blockIdx.x;
    const int tl = blk & 3; const int bm = blk >> 2;
    const int it = tl >> 1, jt = tl & 1;
    const int b = bm / nN, m = bm % nN;
    const int c = tid & 31;
    const int g = tid >> 5;
    const int i3 = g >> 1, j2 = g & 1;     // wave = (c x j2), i3 wave-uniform
    const int il0 = i3 * 6, jl0 = j2 * 12;
    const size_t posbase = (size_t)b * SB_ + (size_t)m * nC;

    float acc[6][12];
    #pragma unroll
    for (int l = 0; l < 6; ++l)
        #pragma unroll
        for (int u = 0; u < 12; ++u) acc[l][u] = 0.f;

    for (int kc = 0; kc < 6; ++kc) {
        if (kc) __syncthreads();
        #pragma unroll
        for (int rr = 0; rr < 6; ++rr) {          // V: 24i x 8k x 32c
            int q = rr * 256 + tid; int pos = q >> 3, cq = q & 7;
            int ii = pos >> 3, kk = pos & 7;
            float4 a = *(const float4*)(v + posbase + (size_t)(it * 24 + ii) * SI_
                                          + (size_t)(kc * 8 + kk) * SJ_ + cq * 4);
            float* dst = Vt + kk * 807 + (cq * 4) * 25 + ii;
            dst[0] = a.x; dst[25] = a.y; dst[50] = a.z; dst[75] = a.w;
        }
        #pragma unroll
        for (int rr = 0; rr < 6; ++rr) {          // W: 8k x 24j x 32c
            int q = rr * 256 + tid; int pos = q >> 3, cq = q & 7;
            int kk = pos / 24, jj = pos - kk * 24;
            float4 a = *(const float4*)(w + posbase + (size_t)(kc * 8 + kk) * SI_
                                          + (size_t)(jt * 24 + jj) * SJ_ + cq * 4);
            float* dst = Wt + kk * 807 + (cq * 4) * 25 + jj;
            dst[0] = a.x; dst[25] = a.y; dst[50] = a.z; dst[75] = a.w;
        }
        __syncthreads();
        #pragma unroll
        for (int kk = 0; kk < 8; ++kk) {
            float vf[6], wf[12];
            #pragma unroll
            for (int l = 0; l < 6; ++l) vf[l] = Vt[kk * 807 + c * 25 + il0 + l];
            #pragma unroll
            for (int u = 0; u < 12; ++u) wf[u] = Wt[kk * 807 + c * 25 + jl0 + u];
            #pragma unroll
            for (int l = 0; l < 6; ++l)
                #pragma unroll
                for (int u = 0; u < 12; ++u)
                    acc[l][u] = fmaf(vf[l], wf[u], acc[l][u]);
        }
    }
    __syncthreads();                               // staging area now reusable

    // Wo * (1/48) -> lds[9504..10527]
    #pragma unroll
    for (int e = 0; e < 4; ++e)
        lds[9504 + e * 256 + tid] = Wo[e * 256 + tid] * (1.f / nN);

    const int ptE = tid >> 3, dqE = tid & 7, d0 = dqE * 4;
    const float4 b4 = *(const float4*)(bo + d0);
    const float vmm = vm[b * nN + m];

    for (int h = 0; h < 2; ++h) {
        if ((i3 >> 1) == h) {                      // write this half's z
            int r0 = il0 - 12 * h;                 // 0 or 6
            #pragma unroll
            for (int l = 0; l < 6; ++l)
                #pragma unroll
                for (int u = 0; u < 12; ++u)
                    lds[((r0 + l) * 24 + jl0 + u) * 33 + c] = acc[l][u];
        }
        __syncthreads();

        float oac[9][4];
        #pragma unroll
        for (int u = 0; u < 9; ++u)
            #pragma unroll
            for (int d = 0; d < 4; ++d) oac[u][d] = 0.f;
        #pragma unroll
        for (int c2 = 0; c2 < 32; ++c2) {
            float4 wo4 = *(const float4*)(lds + 9504 + c2 * 32 + d0);
            float zv[9];
            #pragma unroll
            for (int u = 0; u < 9; ++u) zv[u] = lds[(ptE * 9 + u) * 33 + c2];
            #pragma unroll
            for (int u = 0; u < 9; ++u) {
                oac[u][0] = fmaf(zv[u], wo4.x, oac[u][0]);
                oac[u][1] = fmaf(zv[u], wo4.y, oac[u][1]);
                oac[u][2] = fmaf(zv[u], wo4.z, oac[u][2]);
                oac[u][3] = fmaf(zv[u], wo4.w, oac[u][3]);
            }
        }
        #pragma unroll
        for (int u = 0; u < 9; ++u) {
            int p = ptE * 9 + u;
            int rl = p / 24, jl = p - rl * 24;
            int gi = it * 24 + 12 * h + rl, gj = jt * 24 + jl;
            float mk = vm[b * nN + gi] * vm[b * nN + gj] * vmm;
            float4 o4;
            o4.x = fmaxf(oac[u][0] + b4.x, 0.f) * mk;
            o4.y = fmaxf(oac[u][1] + b4.y, 0.f) * mk;
            o4.z = fmaxf(oac[u][2] + b4.z, 0.f) * mk;
            o4.w = fmaxf(oac[u][3] + b4.w, 0.f) * mk;
            *(float4*)(tout + posbase + (size_t)gi * SI_ + (size_t)gj * SJ_ + d0) = o4;
        }
        if (h == 0) __syncthreads();               // before half-1 overwrites z
    }
}

// ---------------------------------------------------------------------------
// Final snconv2 (C_out = 16), masked, direct to d_out. [c][pos] b128 sweeps.
__global__ __launch_bounds__(256) void k_final(
    const float* __restrict__ t, const float* __restrict__ vm,
    const float* __restrict__ drp, const float* __restrict__ ccp, const float* __restrict__ tbp,
    const float* __restrict__ W0, const float* __restrict__ W1,
    float* __restrict__ out)
{
    __shared__ float sA[32 * CS_], sB[32 * CS_];
    const int tid = threadIdx.x;
    const long base = (long)blockIdx.x * 128;
    for (int rep = 0; rep < 4; ++rep) {
        int q = rep * 256 + tid; int pl = q >> 3, cq = q & 7;
        long p = base + pl;
        float4 a = *(const float4*)(t + p * nC + cq * 4);
        sA[(cq * 4 + 0) * CS_ + pl] = a.x;
        sA[(cq * 4 + 1) * CS_ + pl] = a.y;
        sA[(cq * 4 + 2) * CS_ + pl] = a.z;
        sA[(cq * 4 + 3) * CS_ + pl] = a.w;
        int b, i, j, m; decodePos((int)p, b, i, j, m);
        long pT = ((long)(b * nN + j) * nN + i) * nN + m;
        float4 t4 = *(const float4*)(t + pT * nC + cq * 4);
        sB[(cq * 4 + 0) * CS_ + pl] = t4.x;
        sB[(cq * 4 + 1) * CS_ + pl] = t4.y;
        sB[(cq * 4 + 2) * CS_ + pl] = t4.z;
        sB[(cq * 4 + 3) * CS_ + pl] = t4.w;
    }
    __syncthreads();
    const int pt = tid >> 3, dq = tid & 7;
    const int p0 = pt * 4, d0 = dq * 2;
    float wc[32][2], acc[4][2];
    #pragma unroll
    for (int l = 0; l < 4; ++l) { acc[l][0] = 0.f; acc[l][1] = 0.f; }

    auto loadW = [&](const float* Wp) {
        #pragma unroll
        for (int c2 = 0; c2 < 32; ++c2) {
            float2 q2 = *(const float2*)(Wp + c2 * 16 + d0);
            wc[c2][0] = q2.x; wc[c2][1] = q2.y;
        }
    };
    auto sweep = [&](const float* sp) {
        #pragma unroll
        for (int c2 = 0; c2 < 32; ++c2) {
            float4 tv = *(const float4*)(sp + c2 * CS_ + p0);
            acc[0][0] = fmaf(tv.x, wc[c2][0], acc[0][0]); acc[0][1] = fmaf(tv.x, wc[c2][1], acc[0][1]);
            acc[1][0] = fmaf(tv.y, wc[c2][0], acc[1][0]); acc[1][1] = fmaf(tv.y, wc[c2][1], acc[1][1]);
            acc[2][0] = fmaf(tv.z, wc[c2][0], acc[2][0]); acc[2][1] = fmaf(tv.z, wc[c2][1], acc[2][1]);
            acc[3][0] = fmaf(tv.w, wc[c2][0], acc[3][0]); acc[3][1] = fmaf(tv.w, wc[c2][1], acc[3][1]);
        }
    };

    loadW(W0); sweep(sA);
    loadW(W1); sweep(sB);

    #pragma unroll
    for (int l = 0; l < 4; ++l) {
        int p = (int)base + p0 + l;
        int b, i, j, m; decodePos(p, b, i, j, m);
        float2 d2 = *(const float2*)(drp + (size_t)((b * nN + i) * nN + m) * 16 + d0);
        float2 cc2 = *(const float2*)(ccp + (size_t)((b * nN + j) * nN + m) * 16 + d0);
        float2 tb2 = *(const float2*)(tbp + (size_t)(b * nN + m) * 16 + d0);
        float mk = vm[b * nN + i] * vm[b * nN + j] * vm[b * nN + m];
        float2 o2;
        o2.x = (acc[l][0] + d2.x + cc2.x + tb2.x) * mk;
        o2.y = (acc[l][1] + d2.y + cc2.y + tb2.y) * mk;
        *(float2*)(out + (size_t)p * 16 + d0) = o2;
    }
}

} // anonymous namespace

// ---------------------------------------------------------------------------
extern "C" void kernel_launch(void* const* d_in, const int* in_sizes, int n_in,
                              void* d_out, int out_size, void* d_ws, size_t ws_size,
                              hipStream_t stream)
{
    (void)in_sizes; (void)n_in; (void)out_size; (void)ws_size;
    const float* x    = (const float*)d_in[0];
    const void*  mask = d_in[1];
    const float* bW0  = (const float*)d_in[2];
    const float* bb0  = (const float*)d_in[3];
    const float* lvW0 = (const float*)d_in[4];
    const float* lvb0 = (const float*)d_in[5];
    const float* lwW0 = (const float*)d_in[6];
    const float* lwb0 = (const float*)d_in[7];
    const float* loW0 = (const float*)d_in[8];
    const float* lob0 = (const float*)d_in[9];
    const float* bW1  = (const float*)d_in[10];
    const float* bb1  = (const float*)d_in[11];
    const float* lvW1 = (const float*)d_in[12];
    const float* lvb1 = (const float*)d_in[13];
    const float* lwW1 = (const float*)d_in[14];
    const float* lwb1 = (const float*)d_in[15];
    const float* loW1 = (const float*)d_in[16];
    const float* lob1 = (const float*)d_in[17];
    const float* fW   = (const float*)d_in[18];
    const float* fb   = (const float*)d_in[19];

    float* ws  = (float*)d_ws;
    float* t     = ws;                         // 14155776
    float* v     = ws + 14155776L;             // 14155776
    float* w     = ws + 28311552L;             // 14155776
    float* rows  = ws + 42467328L;             // 294912
    float* cols4 = rows + 294912;              // 4 * 294912
    float* diag  = cols4 + 4 * 294912;         // 294912
    float* tot4  = diag + 294912;              // 4 * 6144
    float* dr    = tot4 + 4 * 6144;            // 294912
    float* cc    = dr + 294912;                // 294912
    float* tb    = cc + 294912;                // 6144
    float* S     = tb + 6144;                  // 128
    float* vm    = S + 128;                    // 192
    float* out   = (float*)d_out;

    k_prep<<<1, 256, 0, stream>>>(x, mask, vm, S);
    k_mix0<<<36, 256, 0, stream>>>(x, S, bW0, bb0, dr, cc, tb);
    k_vw<0><<<3456, 256, 0, stream>>>(x, vm, dr, cc, tb, bW0, bW0 + 1024,
                                      lvW0, lvb0, lwW0, lwb0, v, w);
    k_z<<<768, 256, 0, stream>>>(v, w, loW0, lob0, vm, t);
    k_red4<<<768, 256, 0, stream>>>(t, rows, cols4, diag, tot4);
    k_mix<32><<<36, 256, 0, stream>>>(diag, rows, cols4, tot4, bW1, bb1, dr, cc, tb);

    k_vw<1><<<3456, 256, 0, stream>>>(t, vm, dr, cc, tb, bW1, bW1 + 1024,
                                      lvW1, lvb1, lwW1, lwb1, v, w);
    k_z<<<768, 256, 0, stream>>>(v, w, loW1, lob1, vm, t);
    k_red4<<<768, 256, 0, stream>>>(t, rows, cols4, diag, tot4);
    k_mix<16><<<36, 256, 0, stream>>>(diag, rows, cols4, tot4, fW, fb, dr, cc, tb);
    k_final<<<3456, 256, 0, stream>>>(t, vm, dr, cc, tb, fW, fW + 512, out);
}

// Round 8
// 533.715 us; speedup vs baseline: 1.1430x; 1.1430x over previous
//
#include <hip/hip_runtime.h>
#include <cstdint>

// ---------------------------------------------------------------------------
// SnLocalDecoder: B=4, n=48, C=32. Round-8 = R6 composite + two changes:
//  1) k_vw / k_final sweeps read b64 (float2) from the UNCHANGED [pos][34]
//     layout: (4pt+l)*34+2q is 8B-aligned; banks (8pt+K)%32 -> only 2-way
//     (free, m136). Halves sweep LDS instructions. R7's [c][pos] transpose is
//     structurally impossible to make conflict-free for writes (stride must
//     be both 0 mod 4 and 1 mod 8) -- reverted.
//  2) k_z with fused rows/cols/diag/tot partial reductions (R4's version,
//     correctness-proven, ~40us by R5 arithmetic); k_red4 deleted.
// ---------------------------------------------------------------------------

namespace {

constexpr int nB = 4, nN = 48, nC = 32;
constexpr int SJ_ = nN * nC;            // 1536
constexpr int SI_ = nN * SJ_;           // 73728
constexpr long SB_ = (long)nN * SI_;    // 3538944
constexpr int RP_ = 294912;             // rows-partial stride (2 partials)
constexpr int CP_ = 294912;             // cols-partial stride (2 partials)
constexpr int TP_ = 6144;               // tot-partial stride  (4 partials)

__device__ __forceinline__ void decodePos(int p, int& b, int& i, int& j, int& m) {
    m = p % nN; int r = p / nN;
    j = r % nN; r /= nN;
    i = r % nN; b = r / nN;
}

// ---------------------------------------------------------------------------
__global__ __launch_bounds__(256) void k_prep(const float* __restrict__ x,
                                              const void* __restrict__ maskp,
                                              float* __restrict__ vm,
                                              float* __restrict__ S)
{
    __shared__ float vmL[nB * nN];
    const int tid = threadIdx.x;
    const unsigned int w0 = *(const unsigned int*)maskp;
    const bool is_byte = (w0 == 0x01010101u);   // bool-byte layout
    if (tid < nB * nN) {
        int b = tid / nN, i = tid % nN;
        long idx = ((long)(b * nN + i) * nN + i) * nN + i;   // mask[b,i,i,i]
        int bit;
        if (is_byte) bit = (((const unsigned char*)maskp)[idx] != 0);
        else         bit = (((const int*)maskp)[idx] != 0);
        float f = bit ? 1.f : 0.f;
        vm[tid] = f; vmL[tid] = f;
    }
    __syncthreads();
    if (tid < nB * nC) {
        int b = tid >> 5, c = tid & 31;
        float s = 0.f;
        for (int j = 0; j < nN; ++j) s += x[(b * nN + j) * nC + c] * vmL[b * nN + j];
        S[tid] = s;
    }
}

// ---------------------------------------------------------------------------
// Layer-0 small snconv2 terms, closed form from x and S.
__global__ __launch_bounds__(256) void k_mix0(
    const float* __restrict__ x, const float* __restrict__ S,
    const float* __restrict__ Wb, const float* __restrict__ bias,
    float* __restrict__ drp, float* __restrict__ ccp, float* __restrict__ tbp)
{
    __shared__ float W2s[1024], W3s[1024], W4s[1024], W5s[1024], bs[32];
    const int tid = threadIdx.x;
    for (int q = tid; q < 1024; q += 256) {
        W2s[q] = Wb[2048 + q]; W3s[q] = Wb[3072 + q];
        W4s[q] = Wb[4096 + q]; W5s[q] = Wb[5120 + q];
    }
    if (tid < 32) bs[tid] = bias[tid];
    __syncthreads();
    const int id = blockIdx.x * 256 + tid;        // (b*48+i)*48+m
    const int m = id % nN; int r = id / nN; const int i = r % nN; const int b = r / nN;
    float odr[32], occ[32];
    #pragma unroll
    for (int d = 0; d < 32; ++d) { odr[d] = 0.f; occ[d] = 0.f; }
    for (int c2 = 0; c2 < 32; ++c2) {
        float xi = x[(b * nN + i) * nC + c2];
        float xm = x[(b * nN + m) * nC + c2];
        float sc = S[b * nC + c2];
        float A = xi * xi * xm;
        float R = xi * xm * sc * (1.f / nN);
        #pragma unroll
        for (int d = 0; d < 32; ++d) {
            odr[d] = fmaf(A, W2s[c2 * 32 + d], fmaf(R, W3s[c2 * 32 + d], odr[d]));
            occ[d] = fmaf(R, W4s[c2 * 32 + d], occ[d]);
        }
    }
    #pragma unroll
    for (int d = 0; d < 32; d += 4) {
        *(float4*)(drp + (size_t)id * 32 + d) = make_float4(odr[d], odr[d+1], odr[d+2], odr[d+3]);
        *(float4*)(ccp + (size_t)id * 32 + d) = make_float4(occ[d], occ[d+1], occ[d+2], occ[d+3]);
    }
    if (i == 0) {
        float ot[32];
        #pragma unroll
        for (int d = 0; d < 32; ++d) ot[d] = bs[d];
        for (int c2 = 0; c2 < 32; ++c2) {
            float xm = x[(b * nN + m) * nC + c2];
            float sc = S[b * nC + c2];
            float Tc = xm * sc * sc * (1.f / (nN * nN));
            #pragma unroll
            for (int d = 0; d < 32; ++d) ot[d] = fmaf(Tc, W5s[c2 * 32 + d], ot[d]);
        }
        for (int d = 0; d < 32; d += 4)
            *(float4*)(tbp + (size_t)(b * nN + m) * 32 + d) = make_float4(ot[d], ot[d+1], ot[d+2], ot[d+3]);
    }
}

// ---------------------------------------------------------------------------
// Small snconv2 terms from k_z's partial reductions (2 rows, 2 cols, 4 tot).
template <int DOUT>
__global__ __launch_bounds__(256) void k_mix(
    const float* __restrict__ dgp, const float* __restrict__ rw2,
    const float* __restrict__ cl2, const float* __restrict__ tt4,
    const float* __restrict__ Wb, const float* __restrict__ bias,
    float* __restrict__ drp, float* __restrict__ ccp, float* __restrict__ tbp)
{
    __shared__ float W2s[32 * DOUT], W3s[32 * DOUT], W4s[32 * DOUT], W5s[32 * DOUT], bs[DOUT];
    const int tid = threadIdx.x;
    for (int q = tid; q < 32 * DOUT; q += 256) {
        W2s[q] = Wb[2 * 32 * DOUT + q]; W3s[q] = Wb[3 * 32 * DOUT + q];
        W4s[q] = Wb[4 * 32 * DOUT + q]; W5s[q] = Wb[5 * 32 * DOUT + q];
    }
    if (tid < DOUT) bs[tid] = bias[tid];
    __syncthreads();
    const int id = blockIdx.x * 256 + tid;
    const int m = id % nN; int r = id / nN; const int i = r % nN; const int b = r / nN;
    float odr[DOUT], occ[DOUT];
    #pragma unroll
    for (int d = 0; d < DOUT; ++d) { odr[d] = 0.f; occ[d] = 0.f; }
    for (int c2 = 0; c2 < 32; ++c2) {
        size_t q = (size_t)id * 32 + c2;
        float dg = dgp[q];
        float rw = (rw2[q] + rw2[q + RP_]) * (1.f / nN);
        float cl = (cl2[q] + cl2[q + CP_]) * (1.f / nN);
        #pragma unroll
        for (int d = 0; d < DOUT; ++d) {
            odr[d] = fmaf(dg, W2s[c2 * DOUT + d], fmaf(rw, W3s[c2 * DOUT + d], odr[d]));
            occ[d] = fmaf(cl, W4s[c2 * DOUT + d], occ[d]);
        }
    }
    #pragma unroll
    for (int d = 0; d < DOUT; d += 4) {
        *(float4*)(drp + (size_t)id * DOUT + d) = make_float4(odr[d], odr[d+1], odr[d+2], odr[d+3]);
        *(float4*)(ccp + (size_t)id * DOUT + d) = make_float4(occ[d], occ[d+1], occ[d+2], occ[d+3]);
    }
    if (i == 0) {
        float ot[DOUT];
        #pragma unroll
        for (int d = 0; d < DOUT; ++d) ot[d] = bs[d];
        for (int c2 = 0; c2 < 32; ++c2) {
            size_t q = (size_t)(b * nN + m) * 32 + c2;
            float tv = (tt4[q] + tt4[q + TP_] + tt4[q + 2 * TP_] + tt4[q + 3 * TP_])
                       * (1.f / (nN * nN));
            #pragma unroll
            for (int d = 0; d < DOUT; ++d) ot[d] = fmaf(tv, W5s[c2 * DOUT + d], ot[d]);
        }
        for (int d = 0; d < DOUT; d += 4)
            *(float4*)(tbp + (size_t)(b * nN + m) * DOUT + d) = make_float4(ot[d], ot[d+1], ot[d+2], ot[d+3]);
    }
}

// ---------------------------------------------------------------------------
// s = masked(snconv2(t)); v = s@Wv+bv; w = s@Ww+bw.  R6 structure; sweeps
// read b64 (2 channels per inst) from the same [pos][34] layout.
template <int MODE>
__global__ __launch_bounds__(256) void k_vw(
    const float* __restrict__ src, const float* __restrict__ vm,
    const float* __restrict__ drp, const float* __restrict__ ccp, const float* __restrict__ tbp,
    const float* __restrict__ W0, const float* __restrict__ W1,
    const float* __restrict__ Wv, const float* __restrict__ bv,
    const float* __restrict__ Ww, const float* __restrict__ bw,
    float* __restrict__ vout, float* __restrict__ wout)
{
    __shared__ float sA[128 * 34];
    __shared__ float sB[(MODE == 0) ? 64 : 128 * 34];
    __shared__ float sS[128 * 34];
    const int tid = threadIdx.x;
    const long base = (long)blockIdx.x * 128;

    if (MODE == 0) {
        for (int rep = 0; rep < 4; ++rep) {
            int q = rep * 256 + tid; int pl = q >> 3, cq = q & 7;
            int p = (int)base + pl;
            int b, i, j, m; decodePos(p, b, i, j, m);
            float4 xi = *(const float4*)(src + (size_t)(b * nN + i) * nC + cq * 4);
            float4 xj = *(const float4*)(src + (size_t)(b * nN + j) * nC + cq * 4);
            float4 xm = *(const float4*)(src + (size_t)(b * nN + m) * nC + cq * 4);
            int o = pl * 34 + cq * 4;
            sA[o + 0] = xi.x * xj.x * xm.x;
            sA[o + 1] = xi.y * xj.y * xm.y;
            sA[o + 2] = xi.z * xj.z * xm.z;
            sA[o + 3] = xi.w * xj.w * xm.w;
        }
    } else {
        for (int rep = 0; rep < 4; ++rep) {
            int q = rep * 256 + tid; int pl = q >> 3, cq = q & 7;
            long p = base + pl;
            float4 a = *(const float4*)(src + p * nC + cq * 4);
            int o = pl * 34 + cq * 4;
            sA[o + 0] = a.x; sA[o + 1] = a.y; sA[o + 2] = a.z; sA[o + 3] = a.w;
            int b, i, j, m; decodePos((int)p, b, i, j, m);
            long pT = ((long)(b * nN + j) * nN + i) * nN + m;
            float4 t4 = *(const float4*)(src + pT * nC + cq * 4);
            sB[o + 0] = t4.x; sB[o + 1] = t4.y; sB[o + 2] = t4.z; sB[o + 3] = t4.w;
        }
    }
    __syncthreads();

    const int pt = tid >> 3, dq = tid & 7;
    const int p0 = pt * 4, d0 = dq * 4;
    float wc[32][4];
    float acc[4][4];

    auto zeroAcc = [&]() {
        #pragma unroll
        for (int a2 = 0; a2 < 4; ++a2)
            #pragma unroll
            for (int l = 0; l < 4; ++l) acc[a2][l] = 0.f;
    };
    auto loadW = [&](const float* Wp) {
        #pragma unroll
        for (int c2 = 0; c2 < 32; ++c2) {
            float4 q4 = *(const float4*)(Wp + c2 * nC + d0);
            wc[c2][0] = q4.x; wc[c2][1] = q4.y; wc[c2][2] = q4.z; wc[c2][3] = q4.w;
        }
    };
    auto addW = [&](const float* Wp) {
        #pragma unroll
        for (int c2 = 0; c2 < 32; ++c2) {
            float4 q4 = *(const float4*)(Wp + c2 * nC + d0);
            wc[c2][0] += q4.x; wc[c2][1] += q4.y; wc[c2][2] += q4.z; wc[c2][3] += q4.w;
        }
    };
    auto sweep = [&](const float* sp) {           // b64: 2 channels / inst
        #pragma unroll
        for (int cp = 0; cp < 16; ++cp) {
            float2 t0 = *(const float2*)(sp + (p0 + 0) * 34 + cp * 2);
            float2 t1 = *(const float2*)(sp + (p0 + 1) * 34 + cp * 2);
            float2 t2 = *(const float2*)(sp + (p0 + 2) * 34 + cp * 2);
            float2 t3 = *(const float2*)(sp + (p0 + 3) * 34 + cp * 2);
            const int c0 = cp * 2, c1 = cp * 2 + 1;
            #pragma unroll
            for (int d = 0; d < 4; ++d) {
                acc[0][d] = fmaf(t0.x, wc[c0][d], acc[0][d]);
                acc[1][d] = fmaf(t1.x, wc[c0][d], acc[1][d]);
                acc[2][d] = fmaf(t2.x, wc[c0][d], acc[2][d]);
                acc[3][d] = fmaf(t3.x, wc[c0][d], acc[3][d]);
                acc[0][d] = fmaf(t0.y, wc[c1][d], acc[0][d]);
                acc[1][d] = fmaf(t1.y, wc[c1][d], acc[1][d]);
                acc[2][d] = fmaf(t2.y, wc[c1][d], acc[2][d]);
                acc[3][d] = fmaf(t3.y, wc[c1][d], acc[3][d]);
            }
        }
    };

    zeroAcc();
    if (MODE == 0) { loadW(W0); addW(W1); sweep(sA); }
    else           { loadW(W0); sweep(sA); loadW(W1); sweep(sB); }

    // add small terms, mask, stash masked s
    #pragma unroll
    for (int l = 0; l < 4; ++l) {
        int p = (int)base + p0 + l;
        int b, i, j, m; decodePos(p, b, i, j, m);
        float4 d4 = *(const float4*)(drp + (size_t)((b * nN + i) * nN + m) * nC + d0);
        float4 c4 = *(const float4*)(ccp + (size_t)((b * nN + j) * nN + m) * nC + d0);
        float4 t4 = *(const float4*)(tbp + (size_t)(b * nN + m) * nC + d0);
        float mk = vm[b * nN + i] * vm[b * nN + j] * vm[b * nN + m];
        int o = (p0 + l) * 34 + d0;
        sS[o + 0] = (acc[l][0] + d4.x + c4.x + t4.x) * mk;
        sS[o + 1] = (acc[l][1] + d4.y + c4.y + t4.y) * mk;
        sS[o + 2] = (acc[l][2] + d4.z + c4.z + t4.z) * mk;
        sS[o + 3] = (acc[l][3] + d4.w + c4.w + t4.w) * mk;
    }
    __syncthreads();

    // stage B: v then w
    zeroAcc(); loadW(Wv); sweep(sS);
    {
        float4 b4 = *(const float4*)(bv + d0);
        #pragma unroll
        for (int l = 0; l < 4; ++l) {
            float4 o4 = make_float4(acc[l][0] + b4.x, acc[l][1] + b4.y,
                                    acc[l][2] + b4.z, acc[l][3] + b4.w);
            *(float4*)(vout + (size_t)(base + p0 + l) * nC + d0) = o4;
        }
    }
    zeroAcc(); loadW(Ww); sweep(sS);
    {
        float4 b4 = *(const float4*)(bw + d0);
        #pragma unroll
        for (int l = 0; l < 4; ++l) {
            float4 o4 = make_float4(acc[l][0] + b4.x, acc[l][1] + b4.y,
                                    acc[l][2] + b4.z, acc[l][3] + b4.w);
            *(float4*)(wout + (size_t)(base + p0 + l) * nC + d0) = o4;
        }
    }
}

// ---------------------------------------------------------------------------
// z = V*W/n per (b,m); o-mix + relu + mask -> t; fused rows/cols/diag/tot
// partial reductions (no atomics). Tile 24i x 24j x 32c; 768 blocks.
// (R4's correctness-proven version.)
__global__ __launch_bounds__(256, 3) void k_z(
    const float* __restrict__ v, const float* __restrict__ w,
    const float* __restrict__ Wo, const float* __restrict__ bo,
    const float* __restrict__ vm, float* __restrict__ tout,
    float* __restrict__ rows2, float* __restrict__ cols2,
    float* __restrict__ diag_, float* __restrict__ tot4)
{
    __shared__ float lds[12912];           // 51648 B -> 3 blocks/CU
    float* Vt = lds;                       // [kk][c][i]: kk*807 + c*25 + i
    float* Wt = lds + 6456;
    constexpr int ZS = 34;                 // z/out row stride (per position)
    constexpr int ZWO = 9792;              // Wo area
    constexpr int TOT0 = 10816;            // tot scratch [8][32]
    const int tid = threadIdx.x;
    const int blk = blockIdx.x;
    const int tl = blk & 3; const int bm = blk >> 2;
    const int it = tl >> 1, jt = tl & 1;
    const int b = bm / nN, m = bm % nN;
    const int c = tid & 31;
    const int g = tid >> 5;
    const int i3 = g >> 1, j2 = g & 1;     // i3 wave-uniform
    const int il0 = i3 * 6, jl0 = j2 * 12;
    const size_t posbase = (size_t)b * SB_ + (size_t)m * nC;

    float acc[6][12];
    #pragma unroll
    for (int l = 0; l < 6; ++l)
        #pragma unroll
        for (int u = 0; u < 12; ++u) acc[l][u] = 0.f;

    for (int kc = 0; kc < 6; ++kc) {
        if (kc) __syncthreads();
        #pragma unroll
        for (int rr = 0; rr < 6; ++rr) {          // V: 24i x 8k x 32c
            int q = rr * 256 + tid; int pos = q >> 3, cq = q & 7;
            int ii = pos >> 3, kk = pos & 7;
            float4 a = *(const float4*)(v + posbase + (size_t)(it * 24 + ii) * SI_
                                          + (size_t)(kc * 8 + kk) * SJ_ + cq * 4);
            float* dst = Vt + kk * 807 + (cq * 4) * 25 + ii;
            dst[0] = a.x; dst[25] = a.y; dst[50] = a.z; dst[75] = a.w;
        }
        #pragma unroll
        for (int rr = 0; rr < 6; ++rr) {          // W: 8k x 24j x 32c
            int q = rr * 256 + tid; int pos = q >> 3, cq = q & 7;
            int kk = pos / 24, jj = pos - kk * 24;
            float4 a = *(const float4*)(w + posbase + (size_t)(kc * 8 + kk) * SI_
                                          + (size_t)(jt * 24 + jj) * SJ_ + cq * 4);
            float* dst = Wt + kk * 807 + (cq * 4) * 25 + jj;
            dst[0] = a.x; dst[25] = a.y; dst[50] = a.z; dst[75] = a.w;
        }
        __syncthreads();
        #pragma unroll
        for (int kk = 0; kk < 8; ++kk) {
            float vf[6], wf[12];
            #pragma unroll
            for (int l = 0; l < 6; ++l) vf[l] = Vt[kk * 807 + c * 25 + il0 + l];
            #pragma unroll
            for (int u = 0; u < 12; ++u) wf[u] = Wt[kk * 807 + c * 25 + jl0 + u];
            #pragma unroll
            for (int l = 0; l < 6; ++l)
                #pragma unroll
                for (int u = 0; u < 12; ++u)
                    acc[l][u] = fmaf(vf[l], wf[u], acc[l][u]);
        }
    }
    __syncthreads();                               // staging area now reusable

    #pragma unroll
    for (int e = 0; e < 4; ++e)                    // Wo * (1/48)
        lds[ZWO + e * 256 + tid] = Wo[e * 256 + tid] * (1.f / nN);

    const int ptE = tid >> 3, dqE = tid & 7, d0 = dqE * 4;
    const float4 b4 = *(const float4*)(bo + d0);
    const float vmm = vm[b * nN + m];
    float colacc[3] = {0.f, 0.f, 0.f};
    float totacc = 0.f;

    for (int h = 0; h < 2; ++h) {
        if (h) __syncthreads();                    // protect h=0 reduction reads
        if ((i3 >> 1) == h) {                      // write this half's z
            int r0 = il0 - 12 * h;                 // 0 or 6
            #pragma unroll
            for (int l = 0; l < 6; ++l)
                #pragma unroll
                for (int u = 0; u < 12; ++u)
                    lds[((r0 + l) * 24 + jl0 + u) * ZS + c] = acc[l][u];
        }
        __syncthreads();                           // z + wo visible

        float oac[9][4];
        #pragma unroll
        for (int u = 0; u < 9; ++u)
            #pragma unroll
            for (int d = 0; d < 4; ++d) oac[u][d] = 0.f;
        #pragma unroll
        for (int c2 = 0; c2 < 32; ++c2) {
            float4 wo4 = *(const float4*)(lds + ZWO + c2 * 32 + d0);
            float zv[9];
            #pragma unroll
            for (int u = 0; u < 9; ++u) zv[u] = lds[(ptE * 9 + u) * ZS + c2];
            #pragma unroll
            for (int u = 0; u < 9; ++u) {
                oac[u][0] = fmaf(zv[u], wo4.x, oac[u][0]);
                oac[u][1] = fmaf(zv[u], wo4.y, oac[u][1]);
                oac[u][2] = fmaf(zv[u], wo4.z, oac[u][2]);
                oac[u][3] = fmaf(zv[u], wo4.w, oac[u][3]);
            }
        }
        __syncthreads();                           // all z reads done

        #pragma unroll
        for (int u = 0; u < 9; ++u) {
            int p = ptE * 9 + u;
            int rl = p / 24, jl = p - rl * 24;
            int gi = it * 24 + 12 * h + rl, gj = jt * 24 + jl;
            float mk = vm[b * nN + gi] * vm[b * nN + gj] * vmm;
            float4 o4;
            o4.x = fmaxf(oac[u][0] + b4.x, 0.f) * mk;
            o4.y = fmaxf(oac[u][1] + b4.y, 0.f) * mk;
            o4.z = fmaxf(oac[u][2] + b4.z, 0.f) * mk;
            o4.w = fmaxf(oac[u][3] + b4.w, 0.f) * mk;
            *(float4*)(tout + posbase + (size_t)gi * SI_ + (size_t)gj * SJ_ + d0) = o4;
            *(float2*)(lds + p * ZS + d0) = make_float2(o4.x, o4.y);
            *(float2*)(lds + p * ZS + d0 + 2) = make_float2(o4.z, o4.w);
        }
        __syncthreads();                           // out tile visible in LDS

        for (int rd = 0; rd < 2; ++rd) {
            int task = rd * 256 + tid;
            if (task < 384) {
                int i_r = task >> 5, c_r = task & 31;
                float rsum = 0.f;
                #pragma unroll
                for (int jl = 0; jl < 24; ++jl) rsum += lds[(i_r * 24 + jl) * ZS + c_r];
                int gi = it * 24 + 12 * h + i_r;
                rows2[(size_t)jt * RP_ + ((size_t)(b * nN + gi) * nN + m) * nC + c_r] = rsum;
                totacc += rsum;
                if (it == jt)
                    diag_[((size_t)(b * nN + gi) * nN + m) * nC + c_r] =
                        lds[(i_r * 24 + (12 * h + i_r)) * ZS + c_r];
            }
        }
        #pragma unroll
        for (int rr = 0; rr < 3; ++rr) {
            int task = rr * 256 + tid;
            int jl = task >> 5, c_c = task & 31;
            float csum = 0.f;
            #pragma unroll
            for (int il = 0; il < 12; ++il) csum += lds[(il * 24 + jl) * ZS + c_c];
            colacc[rr] += csum;
        }
    }

    #pragma unroll
    for (int rr = 0; rr < 3; ++rr) {
        int task = rr * 256 + tid;
        int jl = task >> 5, c_c = task & 31;
        cols2[(size_t)it * CP_ + ((size_t)(b * nN + jt * 24 + jl) * nN + m) * nC + c_c] = colacc[rr];
    }
    lds[TOT0 + g * 32 + c] = totacc;
    __syncthreads();
    if (tid < 32) {
        float s = 0.f;
        #pragma unroll
        for (int gg = 0; gg < 8; ++gg) s += lds[TOT0 + gg * 32 + tid];
        tot4[(size_t)(it * 2 + jt) * TP_ + (size_t)(b * nN + m) * nC + tid] = s;
    }
}

// ---------------------------------------------------------------------------
// Final snconv2 (C_out = 16), masked, direct to d_out. b64 sweeps.
__global__ __launch_bounds__(256) void k_final(
    const float* __restrict__ t, const float* __restrict__ vm,
    const float* __restrict__ drp, const float* __restrict__ ccp, const float* __restrict__ tbp,
    const float* __restrict__ W0, const float* __restrict__ W1,
    float* __restrict__ out)
{
    __shared__ float sA[128 * 34], sB[128 * 34];
    const int tid = threadIdx.x;
    const long base = (long)blockIdx.x * 128;
    for (int rep = 0; rep < 4; ++rep) {
        int q = rep * 256 + tid; int pl = q >> 3, cq = q & 7;
        long p = base + pl;
        float4 a = *(const float4*)(t + p * nC + cq * 4);
        int o = pl * 34 + cq * 4;
        sA[o + 0] = a.x; sA[o + 1] = a.y; sA[o + 2] = a.z; sA[o + 3] = a.w;
        int b, i, j, m; decodePos((int)p, b, i, j, m);
        long pT = ((long)(b * nN + j) * nN + i) * nN + m;
        float4 t4 = *(const float4*)(t + pT * nC + cq * 4);
        sB[o + 0] = t4.x; sB[o + 1] = t4.y; sB[o + 2] = t4.z; sB[o + 3] = t4.w;
    }
    __syncthreads();
    const int pt = tid >> 3, dq = tid & 7;
    const int p0 = pt * 4, d0 = dq * 2;
    float wc[32][2], acc[4][2];
    #pragma unroll
    for (int l = 0; l < 4; ++l) { acc[l][0] = 0.f; acc[l][1] = 0.f; }

    auto loadW = [&](const float* Wp) {
        #pragma unroll
        for (int c2 = 0; c2 < 32; ++c2) {
            float2 q2 = *(const float2*)(Wp + c2 * 16 + d0);
            wc[c2][0] = q2.x; wc[c2][1] = q2.y;
        }
    };
    auto sweep = [&](const float* sp) {           // b64: 2 channels / inst
        #pragma unroll
        for (int cp = 0; cp < 16; ++cp) {
            float2 t0 = *(const float2*)(sp + (p0 + 0) * 34 + cp * 2);
            float2 t1 = *(const float2*)(sp + (p0 + 1) * 34 + cp * 2);
            float2 t2 = *(const float2*)(sp + (p0 + 2) * 34 + cp * 2);
            float2 t3 = *(const float2*)(sp + (p0 + 3) * 34 + cp * 2);
            const int c0 = cp * 2, c1 = cp * 2 + 1;
            acc[0][0] = fmaf(t0.x, wc[c0][0], acc[0][0]); acc[0][1] = fmaf(t0.x, wc[c0][1], acc[0][1]);
            acc[1][0] = fmaf(t1.x, wc[c0][0], acc[1][0]); acc[1][1] = fmaf(t1.x, wc[c0][1], acc[1][1]);
            acc[2][0] = fmaf(t2.x, wc[c0][0], acc[2][0]); acc[2][1] = fmaf(t2.x, wc[c0][1], acc[2][1]);
            acc[3][0] = fmaf(t3.x, wc[c0][0], acc[3][0]); acc[3][1] = fmaf(t3.x, wc[c0][1], acc[3][1]);
            acc[0][0] = fmaf(t0.y, wc[c1][0], acc[0][0]); acc[0][1] = fmaf(t0.y, wc[c1][1], acc[0][1]);
            acc[1][0] = fmaf(t1.y, wc[c1][0], acc[1][0]); acc[1][1] = fmaf(t1.y, wc[c1][1], acc[1][1]);
            acc[2][0] = fmaf(t2.y, wc[c1][0], acc[2][0]); acc[2][1] = fmaf(t2.y, wc[c1][1], acc[2][1]);
            acc[3][0] = fmaf(t3.y, wc[c1][0], acc[3][0]); acc[3][1] = fmaf(t3.y, wc[c1][1], acc[3][1]);
        }
    };

    loadW(W0); sweep(sA);
    loadW(W1); sweep(sB);

    #pragma unroll
    for (int l = 0; l < 4; ++l) {
        int p = (int)base + p0 + l;
        int b, i, j, m; decodePos(p, b, i, j, m);
        float2 d2 = *(const float2*)(drp + (size_t)((b * nN + i) * nN + m) * 16 + d0);
        float2 cc2 = *(const float2*)(ccp + (size_t)((b * nN + j) * nN + m) * 16 + d0);
        float2 tb2 = *(const float2*)(tbp + (size_t)(b * nN + m) * 16 + d0);
        float mk = vm[b * nN + i] * vm[b * nN + j] * vm[b * nN + m];
        float2 o2;
        o2.x = (acc[l][0] + d2.x + cc2.x + tb2.x) * mk;
        o2.y = (acc[l][1] + d2.y + cc2.y + tb2.y) * mk;
        *(float2*)(out + (size_t)p * 16 + d0) = o2;
    }
}

} // anonymous namespace

// ---------------------------------------------------------------------------
extern "C" void kernel_launch(void* const* d_in, const int* in_sizes, int n_in,
                              void* d_out, int out_size, void* d_ws, size_t ws_size,
                              hipStream_t stream)
{
    (void)in_sizes; (void)n_in; (void)out_size; (void)ws_size;
    const float* x    = (const float*)d_in[0];
    const void*  mask = d_in[1];
    const float* bW0  = (const float*)d_in[2];
    const float* bb0  = (const float*)d_in[3];
    const float* lvW0 = (const float*)d_in[4];
    const float* lvb0 = (const float*)d_in[5];
    const float* lwW0 = (const float*)d_in[6];
    const float* lwb0 = (const float*)d_in[7];
    const float* loW0 = (const float*)d_in[8];
    const float* lob0 = (const float*)d_in[9];
    const float* bW1  = (const float*)d_in[10];
    const float* bb1  = (const float*)d_in[11];
    const float* lvW1 = (const float*)d_in[12];
    const float* lvb1 = (const float*)d_in[13];
    const float* lwW1 = (const float*)d_in[14];
    const float* lwb1 = (const float*)d_in[15];
    const float* loW1 = (const float*)d_in[16];
    const float* lob1 = (const float*)d_in[17];
    const float* fW   = (const float*)d_in[18];
    const float* fb   = (const float*)d_in[19];

    float* ws  = (float*)d_ws;
    float* t     = ws;                          // 14155776
    float* v     = ws + 14155776L;
    float* w     = ws + 28311552L;
    float* rows2 = ws + 42467328L;              // 2 * 294912
    float* cols2 = rows2 + 2 * 294912;          // 2 * 294912
    float* diag  = cols2 + 2 * 294912;          // 294912
    float* tot4  = diag + 294912;               // 4 * 6144
    float* dr    = tot4 + 4 * 6144;             // 294912
    float* cc    = dr + 294912;                 // 294912
    float* tb    = cc + 294912;                 // 6144
    float* S     = tb + 6144;                   // 128
    float* vm    = S + 128;                     // 192
    float* out   = (float*)d_out;

    k_prep<<<1, 256, 0, stream>>>(x, mask, vm, S);
    k_mix0<<<36, 256, 0, stream>>>(x, S, bW0, bb0, dr, cc, tb);
    k_vw<0><<<3456, 256, 0, stream>>>(x, vm, dr, cc, tb, bW0, bW0 + 1024,
                                      lvW0, lvb0, lwW0, lwb0, v, w);
    k_z<<<768, 256, 0, stream>>>(v, w, loW0, lob0, vm, t, rows2, cols2, diag, tot4);
    k_mix<32><<<36, 256, 0, stream>>>(diag, rows2, cols2, tot4, bW1, bb1, dr, cc, tb);

    k_vw<1><<<3456, 256, 0, stream>>>(t, vm, dr, cc, tb, bW1, bW1 + 1024,
                                      lvW1, lvb1, lwW1, lwb1, v, w);
    k_z<<<768, 256, 0, stream>>>(v, w, loW1, lob1, vm, t, rows2, cols2, diag, tot4);
    k_mix<16><<<36, 256, 0, stream>>>(diag, rows2, cols2, tot4, fW, fb, dr, cc, tb);
    k_final<<<3456, 256, 0, stream>>>(t, vm, dr, cc, tb, fW, fW + 512, out);
}

// Round 9
// 531.984 us; speedup vs baseline: 1.1467x; 1.0033x over previous
//
#include <hip/hip_runtime.h>
#include <cstdint>

// ---------------------------------------------------------------------------
// SnLocalDecoder: B=4, n=48, C=32. Round-9 = R8 + one change:
//  k_vw drops the third LDS buffer (sS); masked s is written back into sA
//  after the t/tT sweeps complete (extra barrier). LDS 52.2 -> 34.8 KB
//  (MODE1) / 17.4 KB (MODE0) => 4 blocks/CU at VGPR 128. No register staging
//  of s (R7 showed +16 VGPR costs a wave); no launch_bounds cap (R3/R4/R5
//  showed forced VGPR caps => wc spill => GB-scale WRITE).
//  k_z keeps R8's fused partial reductions (no atomics), k_red4 deleted.
// ---------------------------------------------------------------------------

namespace {

constexpr int nB = 4, nN = 48, nC = 32;
constexpr int SJ_ = nN * nC;            // 1536
constexpr int SI_ = nN * SJ_;           // 73728
constexpr long SB_ = (long)nN * SI_;    // 3538944
constexpr int RP_ = 294912;             // rows-partial stride (2 partials)
constexpr int CP_ = 294912;             // cols-partial stride (2 partials)
constexpr int TP_ = 6144;               // tot-partial stride  (4 partials)

__device__ __forceinline__ void decodePos(int p, int& b, int& i, int& j, int& m) {
    m = p % nN; int r = p / nN;
    j = r % nN; r /= nN;
    i = r % nN; b = r / nN;
}

// ---------------------------------------------------------------------------
__global__ __launch_bounds__(256) void k_prep(const float* __restrict__ x,
                                              const void* __restrict__ maskp,
                                              float* __restrict__ vm,
                                              float* __restrict__ S)
{
    __shared__ float vmL[nB * nN];
    const int tid = threadIdx.x;
    const unsigned int w0 = *(const unsigned int*)maskp;
    const bool is_byte = (w0 == 0x01010101u);   // bool-byte layout
    if (tid < nB * nN) {
        int b = tid / nN, i = tid % nN;
        long idx = ((long)(b * nN + i) * nN + i) * nN + i;   // mask[b,i,i,i]
        int bit;
        if (is_byte) bit = (((const unsigned char*)maskp)[idx] != 0);
        else         bit = (((const int*)maskp)[idx] != 0);
        float f = bit ? 1.f : 0.f;
        vm[tid] = f; vmL[tid] = f;
    }
    __syncthreads();
    if (tid < nB * nC) {
        int b = tid >> 5, c = tid & 31;
        float s = 0.f;
        for (int j = 0; j < nN; ++j) s += x[(b * nN + j) * nC + c] * vmL[b * nN + j];
        S[tid] = s;
    }
}

// ---------------------------------------------------------------------------
// Layer-0 small snconv2 terms, closed form from x and S.
__global__ __launch_bounds__(256) void k_mix0(
    const float* __restrict__ x, const float* __restrict__ S,
    const float* __restrict__ Wb, const float* __restrict__ bias,
    float* __restrict__ drp, float* __restrict__ ccp, float* __restrict__ tbp)
{
    __shared__ float W2s[1024], W3s[1024], W4s[1024], W5s[1024], bs[32];
    const int tid = threadIdx.x;
    for (int q = tid; q < 1024; q += 256) {
        W2s[q] = Wb[2048 + q]; W3s[q] = Wb[3072 + q];
        W4s[q] = Wb[4096 + q]; W5s[q] = Wb[5120 + q];
    }
    if (tid < 32) bs[tid] = bias[tid];
    __syncthreads();
    const int id = blockIdx.x * 256 + tid;        // (b*48+i)*48+m
    const int m = id % nN; int r = id / nN; const int i = r % nN; const int b = r / nN;
    float odr[32], occ[32];
    #pragma unroll
    for (int d = 0; d < 32; ++d) { odr[d] = 0.f; occ[d] = 0.f; }
    for (int c2 = 0; c2 < 32; ++c2) {
        float xi = x[(b * nN + i) * nC + c2];
        float xm = x[(b * nN + m) * nC + c2];
        float sc = S[b * nC + c2];
        float A = xi * xi * xm;
        float R = xi * xm * sc * (1.f / nN);
        #pragma unroll
        for (int d = 0; d < 32; ++d) {
            odr[d] = fmaf(A, W2s[c2 * 32 + d], fmaf(R, W3s[c2 * 32 + d], odr[d]));
            occ[d] = fmaf(R, W4s[c2 * 32 + d], occ[d]);
        }
    }
    #pragma unroll
    for (int d = 0; d < 32; d += 4) {
        *(float4*)(drp + (size_t)id * 32 + d) = make_float4(odr[d], odr[d+1], odr[d+2], odr[d+3]);
        *(float4*)(ccp + (size_t)id * 32 + d) = make_float4(occ[d], occ[d+1], occ[d+2], occ[d+3]);
    }
    if (i == 0) {
        float ot[32];
        #pragma unroll
        for (int d = 0; d < 32; ++d) ot[d] = bs[d];
        for (int c2 = 0; c2 < 32; ++c2) {
            float xm = x[(b * nN + m) * nC + c2];
            float sc = S[b * nC + c2];
            float Tc = xm * sc * sc * (1.f / (nN * nN));
            #pragma unroll
            for (int d = 0; d < 32; ++d) ot[d] = fmaf(Tc, W5s[c2 * 32 + d], ot[d]);
        }
        for (int d = 0; d < 32; d += 4)
            *(float4*)(tbp + (size_t)(b * nN + m) * 32 + d) = make_float4(ot[d], ot[d+1], ot[d+2], ot[d+3]);
    }
}

// ---------------------------------------------------------------------------
// Small snconv2 terms from k_z's partial reductions (2 rows, 2 cols, 4 tot).
template <int DOUT>
__global__ __launch_bounds__(256) void k_mix(
    const float* __restrict__ dgp, const float* __restrict__ rw2,
    const float* __restrict__ cl2, const float* __restrict__ tt4,
    const float* __restrict__ Wb, const float* __restrict__ bias,
    float* __restrict__ drp, float* __restrict__ ccp, float* __restrict__ tbp)
{
    __shared__ float W2s[32 * DOUT], W3s[32 * DOUT], W4s[32 * DOUT], W5s[32 * DOUT], bs[DOUT];
    const int tid = threadIdx.x;
    for (int q = tid; q < 32 * DOUT; q += 256) {
        W2s[q] = Wb[2 * 32 * DOUT + q]; W3s[q] = Wb[3 * 32 * DOUT + q];
        W4s[q] = Wb[4 * 32 * DOUT + q]; W5s[q] = Wb[5 * 32 * DOUT + q];
    }
    if (tid < DOUT) bs[tid] = bias[tid];
    __syncthreads();
    const int id = blockIdx.x * 256 + tid;
    const int m = id % nN; int r = id / nN; const int i = r % nN; const int b = r / nN;
    float odr[DOUT], occ[DOUT];
    #pragma unroll
    for (int d = 0; d < DOUT; ++d) { odr[d] = 0.f; occ[d] = 0.f; }
    for (int c2 = 0; c2 < 32; ++c2) {
        size_t q = (size_t)id * 32 + c2;
        float dg = dgp[q];
        float rw = (rw2[q] + rw2[q + RP_]) * (1.f / nN);
        float cl = (cl2[q] + cl2[q + CP_]) * (1.f / nN);
        #pragma unroll
        for (int d = 0; d < DOUT; ++d) {
            odr[d] = fmaf(dg, W2s[c2 * DOUT + d], fmaf(rw, W3s[c2 * DOUT + d], odr[d]));
            occ[d] = fmaf(cl, W4s[c2 * DOUT + d], occ[d]);
        }
    }
    #pragma unroll
    for (int d = 0; d < DOUT; d += 4) {
        *(float4*)(drp + (size_t)id * DOUT + d) = make_float4(odr[d], odr[d+1], odr[d+2], odr[d+3]);
        *(float4*)(ccp + (size_t)id * DOUT + d) = make_float4(occ[d], occ[d+1], occ[d+2], occ[d+3]);
    }
    if (i == 0) {
        float ot[DOUT];
        #pragma unroll
        for (int d = 0; d < DOUT; ++d) ot[d] = bs[d];
        for (int c2 = 0; c2 < 32; ++c2) {
            size_t q = (size_t)(b * nN + m) * 32 + c2;
            float tv = (tt4[q] + tt4[q + TP_] + tt4[q + 2 * TP_] + tt4[q + 3 * TP_])
                       * (1.f / (nN * nN));
            #pragma unroll
            for (int d = 0; d < DOUT; ++d) ot[d] = fmaf(tv, W5s[c2 * DOUT + d], ot[d]);
        }
        for (int d = 0; d < DOUT; d += 4)
            *(float4*)(tbp + (size_t)(b * nN + m) * DOUT + d) = make_float4(ot[d], ot[d+1], ot[d+2], ot[d+3]);
    }
}

// ---------------------------------------------------------------------------
// s = masked(snconv2(t)); v = s@Wv+bv; w = s@Ww+bw.  R8 structure minus sS:
// masked s overwrites sA after the t/tT sweeps (extra barrier). b64 sweeps.
template <int MODE>
__global__ __launch_bounds__(256) void k_vw(
    const float* __restrict__ src, const float* __restrict__ vm,
    const float* __restrict__ drp, const float* __restrict__ ccp, const float* __restrict__ tbp,
    const float* __restrict__ W0, const float* __restrict__ W1,
    const float* __restrict__ Wv, const float* __restrict__ bv,
    const float* __restrict__ Ww, const float* __restrict__ bw,
    float* __restrict__ vout, float* __restrict__ wout)
{
    __shared__ float sA[128 * 34];
    __shared__ float sB[(MODE == 0) ? 64 : 128 * 34];
    const int tid = threadIdx.x;
    const long base = (long)blockIdx.x * 128;

    if (MODE == 0) {
        for (int rep = 0; rep < 4; ++rep) {
            int q = rep * 256 + tid; int pl = q >> 3, cq = q & 7;
            int p = (int)base + pl;
            int b, i, j, m; decodePos(p, b, i, j, m);
            float4 xi = *(const float4*)(src + (size_t)(b * nN + i) * nC + cq * 4);
            float4 xj = *(const float4*)(src + (size_t)(b * nN + j) * nC + cq * 4);
            float4 xm = *(const float4*)(src + (size_t)(b * nN + m) * nC + cq * 4);
            int o = pl * 34 + cq * 4;
            sA[o + 0] = xi.x * xj.x * xm.x;
            sA[o + 1] = xi.y * xj.y * xm.y;
            sA[o + 2] = xi.z * xj.z * xm.z;
            sA[o + 3] = xi.w * xj.w * xm.w;
        }
    } else {
        for (int rep = 0; rep < 4; ++rep) {
            int q = rep * 256 + tid; int pl = q >> 3, cq = q & 7;
            long p = base + pl;
            float4 a = *(const float4*)(src + p * nC + cq * 4);
            int o = pl * 34 + cq * 4;
            sA[o + 0] = a.x; sA[o + 1] = a.y; sA[o + 2] = a.z; sA[o + 3] = a.w;
            int b, i, j, m; decodePos((int)p, b, i, j, m);
            long pT = ((long)(b * nN + j) * nN + i) * nN + m;
            float4 t4 = *(const float4*)(src + pT * nC + cq * 4);
            sB[o + 0] = t4.x; sB[o + 1] = t4.y; sB[o + 2] = t4.z; sB[o + 3] = t4.w;
        }
    }
    __syncthreads();

    const int pt = tid >> 3, dq = tid & 7;
    const int p0 = pt * 4, d0 = dq * 4;
    float wc[32][4];
    float acc[4][4];

    auto zeroAcc = [&]() {
        #pragma unroll
        for (int a2 = 0; a2 < 4; ++a2)
            #pragma unroll
            for (int l = 0; l < 4; ++l) acc[a2][l] = 0.f;
    };
    auto loadW = [&](const float* Wp) {
        #pragma unroll
        for (int c2 = 0; c2 < 32; ++c2) {
            float4 q4 = *(const float4*)(Wp + c2 * nC + d0);
            wc[c2][0] = q4.x; wc[c2][1] = q4.y; wc[c2][2] = q4.z; wc[c2][3] = q4.w;
        }
    };
    auto addW = [&](const float* Wp) {
        #pragma unroll
        for (int c2 = 0; c2 < 32; ++c2) {
            float4 q4 = *(const float4*)(Wp + c2 * nC + d0);
            wc[c2][0] += q4.x; wc[c2][1] += q4.y; wc[c2][2] += q4.z; wc[c2][3] += q4.w;
        }
    };
    auto sweep = [&](const float* sp) {           // b64: 2 channels / inst
        #pragma unroll
        for (int cp = 0; cp < 16; ++cp) {
            float2 t0 = *(const float2*)(sp + (p0 + 0) * 34 + cp * 2);
            float2 t1 = *(const float2*)(sp + (p0 + 1) * 34 + cp * 2);
            float2 t2 = *(const float2*)(sp + (p0 + 2) * 34 + cp * 2);
            float2 t3 = *(const float2*)(sp + (p0 + 3) * 34 + cp * 2);
            const int c0 = cp * 2, c1 = cp * 2 + 1;
            #pragma unroll
            for (int d = 0; d < 4; ++d) {
                acc[0][d] = fmaf(t0.x, wc[c0][d], acc[0][d]);
                acc[1][d] = fmaf(t1.x, wc[c0][d], acc[1][d]);
                acc[2][d] = fmaf(t2.x, wc[c0][d], acc[2][d]);
                acc[3][d] = fmaf(t3.x, wc[c0][d], acc[3][d]);
                acc[0][d] = fmaf(t0.y, wc[c1][d], acc[0][d]);
                acc[1][d] = fmaf(t1.y, wc[c1][d], acc[1][d]);
                acc[2][d] = fmaf(t2.y, wc[c1][d], acc[2][d]);
                acc[3][d] = fmaf(t3.y, wc[c1][d], acc[3][d]);
            }
        }
    };

    zeroAcc();
    if (MODE == 0) { loadW(W0); addW(W1); sweep(sA); }
    else           { loadW(W0); sweep(sA); loadW(W1); sweep(sB); }

    __syncthreads();                   // all waves done sweeping sA/sB

    // add small terms, mask, write masked s back into sA
    #pragma unroll
    for (int l = 0; l < 4; ++l) {
        int p = (int)base + p0 + l;
        int b, i, j, m; decodePos(p, b, i, j, m);
        float4 d4 = *(const float4*)(drp + (size_t)((b * nN + i) * nN + m) * nC + d0);
        float4 c4 = *(const float4*)(ccp + (size_t)((b * nN + j) * nN + m) * nC + d0);
        float4 t4 = *(const float4*)(tbp + (size_t)(b * nN + m) * nC + d0);
        float mk = vm[b * nN + i] * vm[b * nN + j] * vm[b * nN + m];
        int o = (p0 + l) * 34 + d0;
        sA[o + 0] = (acc[l][0] + d4.x + c4.x + t4.x) * mk;
        sA[o + 1] = (acc[l][1] + d4.y + c4.y + t4.y) * mk;
        sA[o + 2] = (acc[l][2] + d4.z + c4.z + t4.z) * mk;
        sA[o + 3] = (acc[l][3] + d4.w + c4.w + t4.w) * mk;
    }
    __syncthreads();

    // stage B: v then w (both sweep the s now living in sA)
    zeroAcc(); loadW(Wv); sweep(sA);
    {
        float4 b4 = *(const float4*)(bv + d0);
        #pragma unroll
        for (int l = 0; l < 4; ++l) {
            float4 o4 = make_float4(acc[l][0] + b4.x, acc[l][1] + b4.y,
                                    acc[l][2] + b4.z, acc[l][3] + b4.w);
            *(float4*)(vout + (size_t)(base + p0 + l) * nC + d0) = o4;
        }
    }
    zeroAcc(); loadW(Ww); sweep(sA);
    {
        float4 b4 = *(const float4*)(bw + d0);
        #pragma unroll
        for (int l = 0; l < 4; ++l) {
            float4 o4 = make_float4(acc[l][0] + b4.x, acc[l][1] + b4.y,
                                    acc[l][2] + b4.z, acc[l][3] + b4.w);
            *(float4*)(wout + (size_t)(base + p0 + l) * nC + d0) = o4;
        }
    }
}

// ---------------------------------------------------------------------------
// z = V*W/n per (b,m); o-mix + relu + mask -> t; fused rows/cols/diag/tot
// partial reductions (no atomics). Tile 24i x 24j x 32c; 768 blocks.
__global__ __launch_bounds__(256, 3) void k_z(
    const float* __restrict__ v, const float* __restrict__ w,
    const float* __restrict__ Wo, const float* __restrict__ bo,
    const float* __restrict__ vm, float* __restrict__ tout,
    float* __restrict__ rows2, float* __restrict__ cols2,
    float* __restrict__ diag_, float* __restrict__ tot4)
{
    __shared__ float lds[12912];           // 51648 B -> 3 blocks/CU
    float* Vt = lds;                       // [kk][c][i]: kk*807 + c*25 + i
    float* Wt = lds + 6456;
    constexpr int ZS = 34;                 // z/out row stride (per position)
    constexpr int ZWO = 9792;              // Wo area
    constexpr int TOT0 = 10816;            // tot scratch [8][32]
    const int tid = threadIdx.x;
    const int blk = blockIdx.x;
    const int tl = blk & 3; const int bm = blk >> 2;
    const int it = tl >> 1, jt = tl & 1;
    const int b = bm / nN, m = bm % nN;
    const int c = tid & 31;
    const int g = tid >> 5;
    const int i3 = g >> 1, j2 = g & 1;     // i3 wave-uniform
    const int il0 = i3 * 6, jl0 = j2 * 12;
    const size_t posbase = (size_t)b * SB_ + (size_t)m * nC;

    float acc[6][12];
    #pragma unroll
    for (int l = 0; l < 6; ++l)
        #pragma unroll
        for (int u = 0; u < 12; ++u) acc[l][u] = 0.f;

    for (int kc = 0; kc < 6; ++kc) {
        if (kc) __syncthreads();
        #pragma unroll
        for (int rr = 0; rr < 6; ++rr) {          // V: 24i x 8k x 32c
            int q = rr * 256 + tid; int pos = q >> 3, cq = q & 7;
            int ii = pos >> 3, kk = pos & 7;
            float4 a = *(const float4*)(v + posbase + (size_t)(it * 24 + ii) * SI_
                                          + (size_t)(kc * 8 + kk) * SJ_ + cq * 4);
            float* dst = Vt + kk * 807 + (cq * 4) * 25 + ii;
            dst[0] = a.x; dst[25] = a.y; dst[50] = a.z; dst[75] = a.w;
        }
        #pragma unroll
        for (int rr = 0; rr < 6; ++rr) {          // W: 8k x 24j x 32c
            int q = rr * 256 + tid; int pos = q >> 3, cq = q & 7;
            int kk = pos / 24, jj = pos - kk * 24;
            float4 a = *(const float4*)(w + posbase + (size_t)(kc * 8 + kk) * SI_
                                          + (size_t)(jt * 24 + jj) * SJ_ + cq * 4);
            float* dst = Wt + kk * 807 + (cq * 4) * 25 + jj;
            dst[0] = a.x; dst[25] = a.y; dst[50] = a.z; dst[75] = a.w;
        }
        __syncthreads();
        #pragma unroll
        for (int kk = 0; kk < 8; ++kk) {
            float vf[6], wf[12];
            #pragma unroll
            for (int l = 0; l < 6; ++l) vf[l] = Vt[kk * 807 + c * 25 + il0 + l];
            #pragma unroll
            for (int u = 0; u < 12; ++u) wf[u] = Wt[kk * 807 + c * 25 + jl0 + u];
            #pragma unroll
            for (int l = 0; l < 6; ++l)
                #pragma unroll
                for (int u = 0; u < 12; ++u)
                    acc[l][u] = fmaf(vf[l], wf[u], acc[l][u]);
        }
    }
    __syncthreads();                               // staging area now reusable

    #pragma unroll
    for (int e = 0; e < 4; ++e)                    // Wo * (1/48)
        lds[ZWO + e * 256 + tid] = Wo[e * 256 + tid] * (1.f / nN);

    const int ptE = tid >> 3, dqE = tid & 7, d0 = dqE * 4;
    const float4 b4 = *(const float4*)(bo + d0);
    const float vmm = vm[b * nN + m];
    float colacc[3] = {0.f, 0.f, 0.f};
    float totacc = 0.f;

    for (int h = 0; h < 2; ++h) {
        if (h) __syncthreads();                    // protect h=0 reduction reads
        if ((i3 >> 1) == h) {                      // write this half's z
            int r0 = il0 - 12 * h;                 // 0 or 6
            #pragma unroll
            for (int l = 0; l < 6; ++l)
                #pragma unroll
                for (int u = 0; u < 12; ++u)
                    lds[((r0 + l) * 24 + jl0 + u) * ZS + c] = acc[l][u];
        }
        __syncthreads();                           // z + wo visible

        float oac[9][4];
        #pragma unroll
        for (int u = 0; u < 9; ++u)
            #pragma unroll
            for (int d = 0; d < 4; ++d) oac[u][d] = 0.f;
        #pragma unroll
        for (int c2 = 0; c2 < 32; ++c2) {
            float4 wo4 = *(const float4*)(lds + ZWO + c2 * 32 + d0);
            float zv[9];
            #pragma unroll
            for (int u = 0; u < 9; ++u) zv[u] = lds[(ptE * 9 + u) * ZS + c2];
            #pragma unroll
            for (int u = 0; u < 9; ++u) {
                oac[u][0] = fmaf(zv[u], wo4.x, oac[u][0]);
                oac[u][1] = fmaf(zv[u], wo4.y, oac[u][1]);
                oac[u][2] = fmaf(zv[u], wo4.z, oac[u][2]);
                oac[u][3] = fmaf(zv[u], wo4.w, oac[u][3]);
            }
        }
        __syncthreads();                           // all z reads done

        #pragma unroll
        for (int u = 0; u < 9; ++u) {
            int p = ptE * 9 + u;
            int rl = p / 24, jl = p - rl * 24;
            int gi = it * 24 + 12 * h + rl, gj = jt * 24 + jl;
            float mk = vm[b * nN + gi] * vm[b * nN + gj] * vmm;
            float4 o4;
            o4.x = fmaxf(oac[u][0] + b4.x, 0.f) * mk;
            o4.y = fmaxf(oac[u][1] + b4.y, 0.f) * mk;
            o4.z = fmaxf(oac[u][2] + b4.z, 0.f) * mk;
            o4.w = fmaxf(oac[u][3] + b4.w, 0.f) * mk;
            *(float4*)(tout + posbase + (size_t)gi * SI_ + (size_t)gj * SJ_ + d0) = o4;
            *(float2*)(lds + p * ZS + d0) = make_float2(o4.x, o4.y);
            *(float2*)(lds + p * ZS + d0 + 2) = make_float2(o4.z, o4.w);
        }
        __syncthreads();                           // out tile visible in LDS

        for (int rd = 0; rd < 2; ++rd) {
            int task = rd * 256 + tid;
            if (task < 384) {
                int i_r = task >> 5, c_r = task & 31;
                float rsum = 0.f;
                #pragma unroll
                for (int jl = 0; jl < 24; ++jl) rsum += lds[(i_r * 24 + jl) * ZS + c_r];
                int gi = it * 24 + 12 * h + i_r;
                rows2[(size_t)jt * RP_ + ((size_t)(b * nN + gi) * nN + m) * nC + c_r] = rsum;
                totacc += rsum;
                if (it == jt)
                    diag_[((size_t)(b * nN + gi) * nN + m) * nC + c_r] =
                        lds[(i_r * 24 + (12 * h + i_r)) * ZS + c_r];
            }
        }
        #pragma unroll
        for (int rr = 0; rr < 3; ++rr) {
            int task = rr * 256 + tid;
            int jl = task >> 5, c_c = task & 31;
            float csum = 0.f;
            #pragma unroll
            for (int il = 0; il < 12; ++il) csum += lds[(il * 24 + jl) * ZS + c_c];
            colacc[rr] += csum;
        }
    }

    #pragma unroll
    for (int rr = 0; rr < 3; ++rr) {
        int task = rr * 256 + tid;
        int jl = task >> 5, c_c = task & 31;
        cols2[(size_t)it * CP_ + ((size_t)(b * nN + jt * 24 + jl) * nN + m) * nC + c_c] = colacc[rr];
    }
    lds[TOT0 + g * 32 + c] = totacc;
    __syncthreads();
    if (tid < 32) {
        float s = 0.f;
        #pragma unroll
        for (int gg = 0; gg < 8; ++gg) s += lds[TOT0 + gg * 32 + tid];
        tot4[(size_t)(it * 2 + jt) * TP_ + (size_t)(b * nN + m) * nC + tid] = s;
    }
}

// ---------------------------------------------------------------------------
// Final snconv2 (C_out = 16), masked, direct to d_out. b64 sweeps.
__global__ __launch_bounds__(256) void k_final(
    const float* __restrict__ t, const float* __restrict__ vm,
    const float* __restrict__ drp, const float* __restrict__ ccp, const float* __restrict__ tbp,
    const float* __restrict__ W0, const float* __restrict__ W1,
    float* __restrict__ out)
{
    __shared__ float sA[128 * 34], sB[128 * 34];
    const int tid = threadIdx.x;
    const long base = (long)blockIdx.x * 128;
    for (int rep = 0; rep < 4; ++rep) {
        int q = rep * 256 + tid; int pl = q >> 3, cq = q & 7;
        long p = base + pl;
        float4 a = *(const float4*)(t + p * nC + cq * 4);
        int o = pl * 34 + cq * 4;
        sA[o + 0] = a.x; sA[o + 1] = a.y; sA[o + 2] = a.z; sA[o + 3] = a.w;
        int b, i, j, m; decodePos((int)p, b, i, j, m);
        long pT = ((long)(b * nN + j) * nN + i) * nN + m;
        float4 t4 = *(const float4*)(t + pT * nC + cq * 4);
        sB[o + 0] = t4.x; sB[o + 1] = t4.y; sB[o + 2] = t4.z; sB[o + 3] = t4.w;
    }
    __syncthreads();
    const int pt = tid >> 3, dq = tid & 7;
    const int p0 = pt * 4, d0 = dq * 2;
    float wc[32][2], acc[4][2];
    #pragma unroll
    for (int l = 0; l < 4; ++l) { acc[l][0] = 0.f; acc[l][1] = 0.f; }

    auto loadW = [&](const float* Wp) {
        #pragma unroll
        for (int c2 = 0; c2 < 32; ++c2) {
            float2 q2 = *(const float2*)(Wp + c2 * 16 + d0);
            wc[c2][0] = q2.x; wc[c2][1] = q2.y;
        }
    };
    auto sweep = [&](const float* sp) {           // b64: 2 channels / inst
        #pragma unroll
        for (int cp = 0; cp < 16; ++cp) {
            float2 t0 = *(const float2*)(sp + (p0 + 0) * 34 + cp * 2);
            float2 t1 = *(const float2*)(sp + (p0 + 1) * 34 + cp * 2);
            float2 t2 = *(const float2*)(sp + (p0 + 2) * 34 + cp * 2);
            float2 t3 = *(const float2*)(sp + (p0 + 3) * 34 + cp * 2);
            const int c0 = cp * 2, c1 = cp * 2 + 1;
            acc[0][0] = fmaf(t0.x, wc[c0][0], acc[0][0]); acc[0][1] = fmaf(t0.x, wc[c0][1], acc[0][1]);
            acc[1][0] = fmaf(t1.x, wc[c0][0], acc[1][0]); acc[1][1] = fmaf(t1.x, wc[c0][1], acc[1][1]);
            acc[2][0] = fmaf(t2.x, wc[c0][0], acc[2][0]); acc[2][1] = fmaf(t2.x, wc[c0][1], acc[2][1]);
            acc[3][0] = fmaf(t3.x, wc[c0][0], acc[3][0]); acc[3][1] = fmaf(t3.x, wc[c0][1], acc[3][1]);
            acc[0][0] = fmaf(t0.y, wc[c1][0], acc[0][0]); acc[0][1] = fmaf(t0.y, wc[c1][1], acc[0][1]);
            acc[1][0] = fmaf(t1.y, wc[c1][0], acc[1][0]); acc[1][1] = fmaf(t1.y, wc[c1][1], acc[1][1]);
            acc[2][0] = fmaf(t2.y, wc[c1][0], acc[2][0]); acc[2][1] = fmaf(t2.y, wc[c1][1], acc[2][1]);
            acc[3][0] = fmaf(t3.y, wc[c1][0], acc[3][0]); acc[3][1] = fmaf(t3.y, wc[c1][1], acc[3][1]);
        }
    };

    loadW(W0); sweep(sA);
    loadW(W1); sweep(sB);

    #pragma unroll
    for (int l = 0; l < 4; ++l) {
        int p = (int)base + p0 + l;
        int b, i, j, m; decodePos(p, b, i, j, m);
        float2 d2 = *(const float2*)(drp + (size_t)((b * nN + i) * nN + m) * 16 + d0);
        float2 cc2 = *(const float2*)(ccp + (size_t)((b * nN + j) * nN + m) * 16 + d0);
        float2 tb2 = *(const float2*)(tbp + (size_t)(b * nN + m) * 16 + d0);
        float mk = vm[b * nN + i] * vm[b * nN + j] * vm[b * nN + m];
        float2 o2;
        o2.x = (acc[l][0] + d2.x + cc2.x + tb2.x) * mk;
        o2.y = (acc[l][1] + d2.y + cc2.y + tb2.y) * mk;
        *(float2*)(out + (size_t)p * 16 + d0) = o2;
    }
}

} // anonymous namespace

// ---------------------------------------------------------------------------
extern "C" void kernel_launch(void* const* d_in, const int* in_sizes, int n_in,
                              void* d_out, int out_size, void* d_ws, size_t ws_size,
                              hipStream_t stream)
{
    (void)in_sizes; (void)n_in; (void)out_size; (void)ws_size;
    const float* x    = (const float*)d_in[0];
    const void*  mask = d_in[1];
    const float* bW0  = (const float*)d_in[2];
    const float* bb0  = (const float*)d_in[3];
    const float* lvW0 = (const float*)d_in[4];
    const float* lvb0 = (const float*)d_in[5];
    const float* lwW0 = (const float*)d_in[6];
    const float* lwb0 = (const float*)d_in[7];
    const float* loW0 = (const float*)d_in[8];
    const float* lob0 = (const float*)d_in[9];
    const float* bW1  = (const float*)d_in[10];
    const float* bb1  = (const float*)d_in[11];
    const float* lvW1 = (const float*)d_in[12];
    const float* lvb1 = (const float*)d_in[13];
    const float* lwW1 = (const float*)d_in[14];
    const float* lwb1 = (const float*)d_in[15];
    const float* loW1 = (const float*)d_in[16];
    const float* lob1 = (const float*)d_in[17];
    const float* fW   = (const float*)d_in[18];
    const float* fb   = (const float*)d_in[19];

    float* ws  = (float*)d_ws;
    float* t     = ws;                          // 14155776
    float* v     = ws + 14155776L;
    float* w     = ws + 28311552L;
    float* rows2 = ws + 42467328L;              // 2 * 294912
    float* cols2 = rows2 + 2 * 294912;          // 2 * 294912
    float* diag  = cols2 + 2 * 294912;          // 294912
    float* tot4  = diag + 294912;               // 4 * 6144
    float* dr    = tot4 + 4 * 6144;             // 294912
    float* cc    = dr + 294912;                 // 294912
    float* tb    = cc + 294912;                 // 6144
    float* S     = tb + 6144;                   // 128
    float* vm    = S + 128;                     // 192
    float* out   = (float*)d_out;

    k_prep<<<1, 256, 0, stream>>>(x, mask, vm, S);
    k_mix0<<<36, 256, 0, stream>>>(x, S, bW0, bb0, dr, cc, tb);
    k_vw<0><<<3456, 256, 0, stream>>>(x, vm, dr, cc, tb, bW0, bW0 + 1024,
                                      lvW0, lvb0, lwW0, lwb0, v, w);
    k_z<<<768, 256, 0, stream>>>(v, w, loW0, lob0, vm, t, rows2, cols2, diag, tot4);
    k_mix<32><<<36, 256, 0, stream>>>(diag, rows2, cols2, tot4, bW1, bb1, dr, cc, tb);

    k_vw<1><<<3456, 256, 0, stream>>>(t, vm, dr, cc, tb, bW1, bW1 + 1024,
                                      lvW1, lvb1, lwW1, lwb1, v, w);
    k_z<<<768, 256, 0, stream>>>(v, w, loW1, lob1, vm, t, rows2, cols2, diag, tot4);
    k_mix<16><<<36, 256, 0, stream>>>(diag, rows2, cols2, tot4, fW, fb, dr, cc, tb);
    k_final<<<3456, 256, 0, stream>>>(t, vm, dr, cc, tb, fW, fW + 512, out);
}